// Round 12
// baseline (6906.068 us; speedup 1.0000x reference)
//
#include <hip/hip_runtime.h>

// SpikeMLP — R12: frozen bit-exact chain (panels 512/512, single-acc ascending
// FMA; fp32 ufunc recurrence, contraction off) with:
//   - 8x8 acc/thread (tile 128x128): 0.75 LDS-B/FMA, A kept bf16 in LDS
//   - n-split W reads (tx*4, tx*4+64): 2-way bank aliasing only (free)
//   - LIF recurrence fused into GEMM epilogue via LDS chunks (R2/R3-validated
//     pattern): no Z round-trip, no separate recur kernels.

typedef __bf16 bf16x8_t __attribute__((ext_vector_type(8)));

static constexpr int BSZ   = 4096;
static constexpr int D_IN  = 1024;
static constexpr int H1    = 1024;
static constexpr int D_OUT = 512;
static constexpr int M_ROWS = BSZ * 16;   // 65536, m = b*16 + t

// ---------------------------------------------------------------------------
// pack X [B, D_in, T=16] f32 -> A [m = b*16 + t][d] bf16 (spikes exactly 0/1)
// ---------------------------------------------------------------------------
__global__ void pack_x(const float* __restrict__ X, __bf16* __restrict__ A) {
    const int P = blockIdx.x * 256 + threadIdx.x;     // P = b*1024 + d
    const int b = P >> 10, d = P & 1023;
    const float4* xp = (const float4*)(X + (size_t)P * 16);
    float4 x0 = xp[0], x1 = xp[1], x2 = xp[2], x3 = xp[3];
    const float v[16] = {x0.x, x0.y, x0.z, x0.w, x1.x, x1.y, x1.z, x1.w,
                         x2.x, x2.y, x2.z, x2.w, x3.x, x3.y, x3.z, x3.w};
#pragma unroll
    for (int t = 0; t < 16; ++t)
        A[((size_t)(b * 16 + t)) * 1024 + d] = (__bf16)v[t];
}

// ---------------------------------------------------------------------------
// Fused GEMM + LIF. C-chain (frozen): pacc = fma(a_k, w_k, pacc) ascending;
// tot += pacc at k=512,1024. Tile 128(M) x 128(N), 256 thr, 8x8/thread.
// Epilogue: 4 chunks of 32 n-cols: z -> LDS -> per-(b,n) fp32 scan -> spikes.
// ---------------------------------------------------------------------------
template <bool IS_OUT>
__global__ __launch_bounds__(256, 2) void gemm_fused(
    const __bf16* __restrict__ A,    // [M, 1024] spikes (exactly 0/1)
    const float* __restrict__ W,     // [N, 1024] fp32 weights (raw input)
    const float* __restrict__ bias,  // [N]
    __bf16* __restrict__ S,          // hidden: [M, 1024] spikes out
    float* __restrict__ Out) {       // output layer: [B, 512]
#pragma clang fp contract(off)
    // staging: As bf16[32][128] (8 KB) + Ws f32[32][128] (16 KB) = 24576 B
    // epilogue: zb f32[128][33] (16896 B) + sb bf16[128][32] (8192 B) = 25088 B
    __shared__ __attribute__((aligned(16))) char lds[25088];
    __bf16 (*As)[128] = (__bf16(*)[128])lds;
    float  (*Ws)[128] = (float(*)[128])(lds + 8192);
    float  (*zb)[33]  = (float(*)[33])lds;
    __bf16 (*sb)[32]  = (__bf16(*)[32])(lds + 16896);

    const int tid = threadIdx.x;
    const int tx = tid & 15, ty = tid >> 4;
    const int m0 = blockIdx.x * 128, n0 = blockIdx.y * 128;

    const int arow = tid & 127, akh = tid >> 7;    // staging row / k-half
    const __bf16* Ab = A + (size_t)(m0 + arow) * 1024 + akh * 16;
    const float*  Wb = W + (size_t)(n0 + arow) * 1024 + akh * 16;

    float pacc[8][8] = {};   // current-panel accumulators
    float tot[8][8]  = {};   // sum of completed panels

    for (int kt = 0; kt < 32; ++kt) {
        const int k0 = kt * 32;
        bf16x8_t av0 = *(const bf16x8_t*)(Ab + k0);
        bf16x8_t av1 = *(const bf16x8_t*)(Ab + k0 + 8);
        float4 wv0 = *(const float4*)(Wb + k0);
        float4 wv1 = *(const float4*)(Wb + k0 + 4);
        float4 wv2 = *(const float4*)(Wb + k0 + 8);
        float4 wv3 = *(const float4*)(Wb + k0 + 12);
        __syncthreads();                 // previous tile fully consumed
#pragma unroll
        for (int e = 0; e < 8; ++e) {
            As[akh * 16 + e][arow]     = av0[e];
            As[akh * 16 + 8 + e][arow] = av1[e];
        }
        {
            const float wf[16] = {wv0.x, wv0.y, wv0.z, wv0.w,
                                  wv1.x, wv1.y, wv1.z, wv1.w,
                                  wv2.x, wv2.y, wv2.z, wv2.w,
                                  wv3.x, wv3.y, wv3.z, wv3.w};
#pragma unroll
            for (int e = 0; e < 16; ++e)
                Ws[akh * 16 + e][arow] = wf[e];
        }
        __syncthreads();

#pragma unroll
        for (int kk = 0; kk < 32; ++kk) {          // strictly k-ascending
            bf16x8_t a8 = *(const bf16x8_t*)&As[kk][ty * 8];
            float4 w0 = *(const float4*)&Ws[kk][tx * 4];
            float4 w1 = *(const float4*)&Ws[kk][tx * 4 + 64];
            float a[8];
#pragma unroll
            for (int i = 0; i < 8; ++i) a[i] = (float)a8[i];   // exact (0/1)
            const float w[8] = {w0.x, w0.y, w0.z, w0.w, w1.x, w1.y, w1.z, w1.w};
#pragma unroll
            for (int i = 0; i < 8; ++i)
#pragma unroll
                for (int j = 0; j < 8; ++j)
                    pacc[i][j] = __builtin_fmaf(a[i], w[j], pacc[i][j]);
        }

        if (kt == 15 || kt == 31) {      // frozen panel flush: k = 512, 1024
#pragma unroll
            for (int i = 0; i < 8; ++i)
#pragma unroll
                for (int j = 0; j < 8; ++j) {
                    tot[i][j] = tot[i][j] + pacc[i][j];
                    pacc[i][j] = 0.0f;
                }
        }
    }

    // ---- fused epilogue: 4 chunks of 32 n-cols ----------------------------
    // thread (tx,ty) holds rows m_local = ty*8+i; cols tx*4+j (j<4) and
    // 64+tx*4+(j-4) (j>=4). chunk ch: writers tx>>3 == (ch&1), group = ch>>1.
    const int sc_b = tid >> 5;       // 0..7  (local batch)
    const int sc_n = tid & 31;       // 0..31 (col within chunk)
#pragma unroll
    for (int ch = 0; ch < 4; ++ch) {
        __syncthreads();             // LDS region free (staging / prev chunk)
        if ((tx >> 3) == (ch & 1)) {
            const int g  = (ch >> 1) * 4;
            const int cc = (tx & 7) * 4;
#pragma unroll
            for (int i = 0; i < 8; ++i)
#pragma unroll
                for (int c = 0; c < 4; ++c)
                    zb[ty * 8 + i][cc + c] = tot[i][g + c];
        }
        __syncthreads();
        {
            const int n = n0 + ch * 32 + sc_n;
            const float bb = bias[n];
            float c = 0.f, v = 0.f, s = 0.f, acm = 0.f;
#pragma unroll
            for (int t = 0; t < 16; ++t) {         // fp32 ufunc order (frozen)
                const float z = zb[sc_b * 16 + t][sc_n];
                const float t1 = c * 0.5f;
                const float t2 = t1 + z;
                c = t2 + bb;
                const float u1 = v * 0.75f;
                const float u2 = u1 * (1.0f - s);
                v = u2 + c;
                s = (v > 0.5f) ? 1.0f : 0.0f;
                if (!IS_OUT) sb[sc_b * 16 + t][sc_n] = (__bf16)s;   // exact 0/1
                else         acm += s;
            }
            if (IS_OUT)
                Out[(size_t)(blockIdx.x * 8 + sc_b) * 512 + n] = acm * 0.0625f;
        }
        if (!IS_OUT) {
            __syncthreads();
            // cooperative coalesced spike store: 128 rows x 32 bf16
            const int r = tid & 127, hf = tid >> 7;
            bf16x8_t s0 = *(const bf16x8_t*)&sb[r][hf * 16];
            bf16x8_t s1 = *(const bf16x8_t*)&sb[r][hf * 16 + 8];
            __bf16* dst = S + (size_t)(m0 + r) * 1024 + n0 + ch * 32 + hf * 16;
            *(bf16x8_t*)dst       = s0;
            *(bf16x8_t*)(dst + 8) = s1;
        }
    }
}

// ---------------------------------------------------------------------------
extern "C" void kernel_launch(void* const* d_in, const int* in_sizes, int n_in,
                              void* d_out, int out_size, void* d_ws, size_t ws_size,
                              hipStream_t stream) {
    const float* X  = (const float*)d_in[0];
    const float* W1 = (const float*)d_in[1];
    const float* b1 = (const float*)d_in[2];
    const float* W2 = (const float*)d_in[3];
    const float* b2 = (const float*)d_in[4];
    const float* Wo = (const float*)d_in[5];
    const float* bo = (const float*)d_in[6];

    char* ws = (char*)d_ws;
    __bf16* A1 = (__bf16*)ws;                      // 128 MiB (reused as S2)
    __bf16* S1 = (__bf16*)(ws + (128ull << 20));   // 128 MiB
    __bf16* S2 = A1;

    pack_x<<<(BSZ * D_IN) / 256, 256, 0, stream>>>(X, A1);

    // layer 1: A1 -> S1
    gemm_fused<false><<<dim3(M_ROWS / 128, H1 / 128), 256, 0, stream>>>(
        A1, W1, b1, S1, nullptr);
    // layer 2: S1 -> S2 (reuses A1)
    gemm_fused<false><<<dim3(M_ROWS / 128, H1 / 128), 256, 0, stream>>>(
        S1, W2, b2, S2, nullptr);
    // output layer: S2 -> out
    gemm_fused<true><<<dim3(M_ROWS / 128, D_OUT / 128), 256, 0, stream>>>(
        S2, Wo, bo, nullptr, (float*)d_out);
}

// Round 13
// 4278.583 us; speedup vs baseline: 1.6141x; 1.6141x over previous
//
#include <hip/hip_runtime.h>

// SpikeMLP — R13: frozen bit-exact chain (panels 512/512, single-acc ascending
// FMA; fp32 ufunc recurrence, contraction off).
// Perf structure: tile 128(M)x64(N), 8x4/thread (R11's no-spill register
// budget), A staged as bf16 (1.0 LDS-B/FMA), fused LIF epilogue (no Z buffer,
// no recur kernels), grid x = n-block for A L2 reuse.
// R12 post-mortem: 8x8 tile spilled to scratch (WRITE_SIZE 3.6 GB) — keep
// accumulators <= 64 floats/thread.

typedef __bf16 bf16x8_t __attribute__((ext_vector_type(8)));

static constexpr int BSZ   = 4096;
static constexpr int D_IN  = 1024;
static constexpr int H1    = 1024;
static constexpr int D_OUT = 512;
static constexpr int M_ROWS = BSZ * 16;   // 65536, m = b*16 + t

// ---------------------------------------------------------------------------
// pack X [B, D_in, T=16] f32 -> A [m = b*16 + t][d] bf16 (spikes exactly 0/1)
// ---------------------------------------------------------------------------
__global__ void pack_x(const float* __restrict__ X, __bf16* __restrict__ A) {
    const int P = blockIdx.x * 256 + threadIdx.x;     // P = b*1024 + d
    const int b = P >> 10, d = P & 1023;
    const float4* xp = (const float4*)(X + (size_t)P * 16);
    float4 x0 = xp[0], x1 = xp[1], x2 = xp[2], x3 = xp[3];
    const float v[16] = {x0.x, x0.y, x0.z, x0.w, x1.x, x1.y, x1.z, x1.w,
                         x2.x, x2.y, x2.z, x2.w, x3.x, x3.y, x3.z, x3.w};
#pragma unroll
    for (int t = 0; t < 16; ++t)
        A[((size_t)(b * 16 + t)) * 1024 + d] = (__bf16)v[t];
}

// ---------------------------------------------------------------------------
// Fused GEMM + LIF. Chain (FROZEN): pacc = fma(a_k, w_k, pacc), k ascending;
// tot += pacc after k=512 (kt=15) and k=1024 (kt=31).
// Tile 128(M) x 64(N), 256 thr, 8x4/thread. BK=32, k-major LDS, A bf16.
// Epilogue: 2 chunks of 32 n-cols: tot -> LDS -> fp32 ufunc scan -> spikes.
// ---------------------------------------------------------------------------
template <bool IS_OUT>
__global__ __launch_bounds__(256) void gemm_fused(
    const __bf16* __restrict__ A,    // [M, 1024] spikes (exactly 0/1)
    const float* __restrict__ W,     // [N, 1024] fp32 weights (raw input)
    const float* __restrict__ bias,  // [N]
    __bf16* __restrict__ S,          // hidden: [M, 1024] spikes out
    float* __restrict__ Out) {       // output layer: [B, 512]
#pragma clang fp contract(off)
    // staging: As bf16[32][128] (8 KB) + Ws f32[32][64] (8 KB) = 16384 B
    // epilogue overlay: zb f32[128][33] (16896 B) + sb bf16[128][32] (8 KB)
    __shared__ __attribute__((aligned(16))) char lds[24896];
    __bf16 (*As)[128] = (__bf16(*)[128])lds;
    float  (*Ws)[64]  = (float(*)[64])(lds + 8192);
    float  (*zb)[33]  = (float(*)[33])lds;
    __bf16 (*sb)[32]  = (__bf16(*)[32])(lds + 16896);

    const int tid = threadIdx.x;
    const int tx = tid & 15;         // n: cols tx*4 .. tx*4+3 (contiguous)
    const int ty = tid >> 4;         // m: rows ty*8 .. ty*8+7
    const int n0 = blockIdx.x * 64;  // x = n-block (A L2 reuse across blocks)
    const int m0 = blockIdx.y * 128;

    const int arow = tid & 127, akh = tid >> 7;   // A staging: row, k-half
    const int wrow = tid & 63,  wks = tid >> 6;   // W staging: row, k-quarter
    const __bf16* Ab = A + (size_t)(m0 + arow) * 1024 + akh * 16;
    const float*  Wb = W + (size_t)(n0 + wrow) * 1024 + wks * 8;

    float pacc[8][4] = {};   // current-panel accumulators
    float tot[8][4]  = {};   // sum of completed panels

    for (int kt = 0; kt < 32; ++kt) {
        const int k0 = kt * 32;
        bf16x8_t av0 = *(const bf16x8_t*)(Ab + k0);
        bf16x8_t av1 = *(const bf16x8_t*)(Ab + k0 + 8);
        float4   wv0 = *(const float4*)(Wb + k0);
        float4   wv1 = *(const float4*)(Wb + k0 + 4);
        __syncthreads();                 // previous tile fully consumed
#pragma unroll
        for (int e = 0; e < 8; ++e) {
            As[akh * 16 + e][arow]     = av0[e];
            As[akh * 16 + 8 + e][arow] = av1[e];
        }
        Ws[wks * 8 + 0][wrow] = wv0.x;
        Ws[wks * 8 + 1][wrow] = wv0.y;
        Ws[wks * 8 + 2][wrow] = wv0.z;
        Ws[wks * 8 + 3][wrow] = wv0.w;
        Ws[wks * 8 + 4][wrow] = wv1.x;
        Ws[wks * 8 + 5][wrow] = wv1.y;
        Ws[wks * 8 + 6][wrow] = wv1.z;
        Ws[wks * 8 + 7][wrow] = wv1.w;
        __syncthreads();

#pragma unroll
        for (int kk = 0; kk < 32; ++kk) {          // strictly k-ascending
            bf16x8_t a8 = *(const bf16x8_t*)&As[kk][ty * 8];
            float4   w4 = *(const float4*)&Ws[kk][tx * 4];
            float a[8];
#pragma unroll
            for (int i = 0; i < 8; ++i) a[i] = (float)a8[i];   // exact (0/1)
            const float w[4] = {w4.x, w4.y, w4.z, w4.w};
#pragma unroll
            for (int i = 0; i < 8; ++i)
#pragma unroll
                for (int j = 0; j < 4; ++j)
                    pacc[i][j] = __builtin_fmaf(a[i], w[j], pacc[i][j]);
        }

        if (kt == 15 || kt == 31) {      // frozen panel flush: k = 512, 1024
#pragma unroll
            for (int i = 0; i < 8; ++i)
#pragma unroll
                for (int j = 0; j < 4; ++j) {
                    tot[i][j] = tot[i][j] + pacc[i][j];
                    pacc[i][j] = 0.0f;
                }
        }
    }

    // ---- fused epilogue: 2 chunks of 32 n-cols ----------------------------
    const int sc_b = tid >> 5;       // 0..7  (local batch)
    const int sc_n = tid & 31;       // 0..31 (col within chunk)
#pragma unroll
    for (int ch = 0; ch < 2; ++ch) {
        __syncthreads();             // staging / previous chunk fully read
        if ((tx >> 3) == ch) {       // writers: tx in [ch*8, ch*8+8)
            const int cc = (tx & 7) * 4;
#pragma unroll
            for (int i = 0; i < 8; ++i)
#pragma unroll
                for (int c = 0; c < 4; ++c)
                    zb[ty * 8 + i][cc + c] = tot[i][c];
        }
        __syncthreads();
        {
            const int n = n0 + ch * 32 + sc_n;
            const float bb = bias[n];
            float c = 0.f, v = 0.f, s = 0.f, acm = 0.f;
#pragma unroll
            for (int t = 0; t < 16; ++t) {         // fp32 ufunc order (frozen)
                const float z = zb[sc_b * 16 + t][sc_n];
                const float t1 = c * 0.5f;
                const float t2 = t1 + z;
                c = t2 + bb;
                const float u1 = v * 0.75f;
                const float u2 = u1 * (1.0f - s);
                v = u2 + c;
                s = (v > 0.5f) ? 1.0f : 0.0f;
                if (!IS_OUT) sb[sc_b * 16 + t][sc_n] = (__bf16)s;   // exact 0/1
                else         acm += s;
            }
            if (IS_OUT)
                Out[(size_t)(blockIdx.y * 8 + sc_b) * 512 + n] = acm * 0.0625f;
        }
        if (!IS_OUT) {
            __syncthreads();
            // cooperative spike store: 128 rows x 32 bf16
            const int r = tid & 127, hf = tid >> 7;
            bf16x8_t s0 = *(const bf16x8_t*)&sb[r][hf * 16];
            bf16x8_t s1 = *(const bf16x8_t*)&sb[r][hf * 16 + 8];
            __bf16* dst = S + (size_t)(m0 + r) * 1024 + n0 + ch * 32 + hf * 16;
            *(bf16x8_t*)dst       = s0;
            *(bf16x8_t*)(dst + 8) = s1;
        }
    }
}

// ---------------------------------------------------------------------------
extern "C" void kernel_launch(void* const* d_in, const int* in_sizes, int n_in,
                              void* d_out, int out_size, void* d_ws, size_t ws_size,
                              hipStream_t stream) {
    const float* X  = (const float*)d_in[0];
    const float* W1 = (const float*)d_in[1];
    const float* b1 = (const float*)d_in[2];
    const float* W2 = (const float*)d_in[3];
    const float* b2 = (const float*)d_in[4];
    const float* Wo = (const float*)d_in[5];
    const float* bo = (const float*)d_in[6];

    char* ws = (char*)d_ws;
    __bf16* A1 = (__bf16*)ws;                      // 128 MiB (reused as S2)
    __bf16* S1 = (__bf16*)(ws + (128ull << 20));   // 128 MiB
    __bf16* S2 = A1;

    pack_x<<<(BSZ * D_IN) / 256, 256, 0, stream>>>(X, A1);

    // layer 1: A1 -> S1
    gemm_fused<false><<<dim3(H1 / 64, M_ROWS / 128), 256, 0, stream>>>(
        A1, W1, b1, S1, nullptr);
    // layer 2: S1 -> S2 (reuses A1)
    gemm_fused<false><<<dim3(H1 / 64, M_ROWS / 128), 256, 0, stream>>>(
        S1, W2, b2, S2, nullptr);
    // output layer: S2 -> out
    gemm_fused<true><<<dim3(D_OUT / 64, M_ROWS / 128), 256, 0, stream>>>(
        S2, Wo, bo, nullptr, (float*)d_out);
}